// Round 10
// baseline (1638.487 us; speedup 1.0000x reference)
//
#include <hip/hip_runtime.h>

#define R_ET 8
#define DH 128
#define AS 1160  // agg LDS row stride in bf16: 9*128 + 8 pad -> 145 chunks (17 mod 32, conflict-free)

typedef __bf16 bf16x8 __attribute__((ext_vector_type(8)));
typedef float f32x4 __attribute__((ext_vector_type(4)));

__device__ __forceinline__ ushort f2bf(float f) {
  unsigned u = __float_as_uint(f);
  u += 0x7fff + ((u >> 16) & 1);  // round-to-nearest-even
  return (ushort)(u >> 16);
}

// ---------------- degree count per (dst, etype) segment ----------------
__global__ void count_kernel(const int* __restrict__ ei, const int* __restrict__ et,
                             int* __restrict__ cnt, int E) {
  int e = blockIdx.x * blockDim.x + threadIdx.x;
  if (e < E) atomicAdd(&cnt[ei[E + e] * R_ET + et[e]], 1);
}

// ---------------- 3-phase exclusive scan over M = N*R segment counts ----------------
__global__ __launch_bounds__(1024) void scan1_kernel(const int* __restrict__ cnt,
                                                     int* __restrict__ off,
                                                     int* __restrict__ bsum, int M) {
  __shared__ int s[1024];
  int tid = threadIdx.x;
  int i = blockIdx.x * 1024 + tid;
  int d = (i < M) ? cnt[i] : 0;
  s[tid] = d;
  __syncthreads();
  for (int step = 1; step < 1024; step <<= 1) {
    int v = (tid >= step) ? s[tid - step] : 0;
    __syncthreads();
    s[tid] += v;
    __syncthreads();
  }
  if (i < M) off[i] = s[tid] - d;
  if (tid == 1023) bsum[blockIdx.x] = s[1023];
}

__global__ __launch_bounds__(1024) void scan2_kernel(int* __restrict__ bsum, int nb) {
  __shared__ int s[1024];
  int tid = threadIdx.x;
  int v = (tid < nb) ? bsum[tid] : 0;
  s[tid] = v;
  __syncthreads();
  for (int step = 1; step < 1024; step <<= 1) {
    int x = (tid >= step) ? s[tid - step] : 0;
    __syncthreads();
    s[tid] += x;
    __syncthreads();
  }
  if (tid < nb) bsum[tid] = s[tid] - v;
}

__global__ __launch_bounds__(1024) void scan3_kernel(int* __restrict__ off,
                                                     int* __restrict__ cursor,
                                                     const int* __restrict__ bsum,
                                                     int M, int E) {
  int i = blockIdx.x * 1024 + threadIdx.x;
  if (i < M) {
    int o = off[i] + bsum[blockIdx.x];
    off[i] = o;
    cursor[i] = o;
  }
  if (i == 0) off[M] = E;
}

// ---------------- place edges into (dst,r)-sorted slots (4B meta = src) ----------------
__global__ void place_kernel(const int* __restrict__ ei, const int* __restrict__ et,
                             int* __restrict__ cursor, int* __restrict__ meta, int E) {
  int e = blockIdx.x * blockDim.x + threadIdx.x;
  if (e >= E) return;
  int src = ei[e], dst = ei[E + e], r = et[e];
  int slot = atomicAdd(&cursor[dst * R_ET + r], 1);
  meta[slot] = src;
}

// ---------------- weight convert+transpose: Wt[mat][n][k] bf16 (plain) ----------------
// mats 0..7 = W[r], mat 8 = root.
__global__ __launch_bounds__(256) void wconv_kernel(const float* __restrict__ root,
                                                    const float* __restrict__ W,
                                                    ushort* __restrict__ Wt) {
  int mat = blockIdx.x;
  const float* src = (mat == 8) ? root : (W + (size_t)mat * DH * DH);
  ushort* dst = Wt + (size_t)mat * DH * DH;
  for (int idx = threadIdx.x; idx < DH * DH; idx += 256) {
    int n = idx >> 7, k = idx & 127;
    dst[n * DH + k] = f2bf(src[k * DH + n]);
  }
}

// ---------------- activation convert (layer 0): fp32 -> bf16 plain ----------------
__global__ __launch_bounds__(256) void aconv_kernel(const float* __restrict__ src,
                                                    ushort* __restrict__ dst, int total) {
  int i4 = (blockIdx.x * 256 + threadIdx.x) * 4;
  if (i4 >= total) return;
  float4 v = *(const float4*)&src[i4];
  *(ushort4*)&dst[i4] = make_ushort4(f2bf(v.x), f2bf(v.y), f2bf(v.z), f2bf(v.w));
}

// ---------------- fused RGCN layer: aggregate-first, 16 dsts per block ----------------
// Phase 1: wave w owns dsts [16b+4w, 16b+4w+4) x 8 relations = 32 contiguous CSR
//   segments; register-accumulates each segment's x[src] mean (fp32), rounds ONCE to
//   bf16 into LDS agg[16][9][128] (row stride AS). Row slot r=8 <- x[dst] (root).
// Phase 2: C[16,128] = agg @ blockdiag(W_0..7, root) via MFMA 16x16x32, K=1152.
//   B-frags streamed from L2-hot Wt. Mid layers: xnext = bf16(relu(C + bias)).
//   Last layer: column sums pooled into upart[blk&63][128].
template <int LAST>
__global__ __launch_bounds__(256) void rgcn_fused(
    const ushort* __restrict__ x, const ushort* __restrict__ Wt,
    const int* __restrict__ offs, const int* __restrict__ meta,
    const float* __restrict__ bias, ushort* __restrict__ xnext,
    float* __restrict__ upart, int N, int M) {
  __shared__ ushort agg[16 * AS];
  const int tid = threadIdx.x;
  const int wid = tid >> 6, lane = tid & 63;

  // zero this wave's 4 rows (no barrier needed before own-phase-1 writes)
  {
    uint* az = (uint*)&agg[(wid * 4) * AS];
    for (int i = lane; i < 4 * AS / 2; i += 64) az[i] = 0;
  }

  // ---- phase 1: segment means ----
  const int dst0 = blockIdx.x * 16 + wid * 4;
  const int s0 = dst0 * R_ET;
  int offreg = offs[min(s0 + min(lane, 64), M)];  // lanes 0..32 used
  int estart = __shfl(offreg, 0);
  int eend = __shfl(offreg, 32);
  int cur = 0;
  int curstart = estart;
  int nxt = __shfl(offreg, 1);
  float sx = 0.f, sy = 0.f;
  for (int base = estart; base < eend; base += 64) {
    int mm = min(64, eend - base);
    int md = (lane < mm) ? meta[base + lane] : 0;
    for (int j = 0; j < mm; j++) {
      int slot = base + j;
      while (slot >= nxt) {  // flush finished segment, advance
        int cnt = nxt - curstart;
        if (cnt > 0) {
          float inv = 1.f / (float)cnt;
          int dloc = wid * 4 + (cur >> 3);
          int r = cur & 7;
          *(uint*)&agg[dloc * AS + r * DH + lane * 2] =
              (uint)f2bf(sx * inv) | ((uint)f2bf(sy * inv) << 16);
        }
        sx = sy = 0.f;
        cur++;
        curstart = nxt;
        nxt = __shfl(offreg, min(cur + 1, 32));
      }
      int src = __shfl(md, j);
      unsigned u = *(const unsigned*)&x[src * DH + lane * 2];
      sx += __uint_as_float(u << 16);
      sy += __uint_as_float(u & 0xffff0000u);
    }
  }
  {  // final flush
    int cnt = nxt - curstart;
    if (cnt > 0) {
      float inv = 1.f / (float)cnt;
      int dloc = wid * 4 + (cur >> 3);
      int r = cur & 7;
      *(uint*)&agg[dloc * AS + r * DH + lane * 2] =
          (uint)f2bf(sx * inv) | ((uint)f2bf(sy * inv) << 16);
    }
  }
  // root rows: agg[dloc][8] = x[dst]
#pragma unroll
  for (int d = 0; d < 4; d++) {
    int dst = dst0 + d;
    if (dst < N) {
      unsigned u = *(const unsigned*)&x[(size_t)dst * DH + lane * 2];
      *(uint*)&agg[(wid * 4 + d) * AS + 8 * DH + lane * 2] = u;
    }
  }
  __syncthreads();

  // ---- phase 2: MFMA ----
  const int l15 = lane & 15, quad = lane >> 4;
  for (int c = 0; c < 2; c++) {
    int ct = wid * 2 + c;
    int col = ct * 16 + l15;
    f32x4 acc = (f32x4){0.f, 0.f, 0.f, 0.f};
#pragma unroll
    for (int r = 0; r < 9; r++) {
      const ushort* wb = Wt + ((size_t)r << 14) + col * DH + quad * 8;
      const ushort* ab = &agg[l15 * AS + r * DH + quad * 8];
#pragma unroll
      for (int kc = 0; kc < 4; kc++) {
        bf16x8 a = *(const bf16x8*)&ab[kc * 32];
        bf16x8 b = *(const bf16x8*)&wb[kc * 32];
        acc = __builtin_amdgcn_mfma_f32_16x16x32_bf16(a, b, acc, 0, 0, 0);
      }
    }
    if (!LAST) {
      float bv = bias[col];
#pragma unroll
      for (int reg = 0; reg < 4; reg++) {
        int dst = blockIdx.x * 16 + quad * 4 + reg;
        if (dst < N) xnext[(size_t)dst * DH + col] = f2bf(fmaxf(acc[reg] + bv, 0.f));
      }
    } else {
      float v = acc[0] + acc[1] + acc[2] + acc[3];
      v += __shfl_xor(v, 16);
      v += __shfl_xor(v, 32);
      if (quad == 0) atomicAdd(&upart[(blockIdx.x & 63) * DH + col], v);
    }
  }
}

// ---------------- final MLP: reduce 64 partials, /N, +bias2, 2-layer MLP ----------
__global__ __launch_bounds__(256) void mlp_kernel(
    const float* __restrict__ upart, const float* __restrict__ bias2,
    const float* __restrict__ fc1w, const float* __restrict__ fc1b,
    const float* __restrict__ fc2w, const float* __restrict__ fc2b,
    float* __restrict__ out, int N) {
  __shared__ float uin[256];
  __shared__ float hred[128];
  int tid = threadIdx.x;
  {
    int g = tid >> 7, col = tid & 127;
    const float* up = upart + (size_t)g * 64 * DH + col;
    float s = 0.f;
#pragma unroll
    for (int p = 0; p < 64; p++) s += up[(size_t)p * DH];
    uin[tid] = s * (1.f / (float)N) + bias2[col];
  }
  __syncthreads();
  if (tid < 128) {
    float s = fc1b[tid];
    for (int i = 0; i < 256; i++) s = fmaf(uin[i], fc1w[i * 128 + tid], s);
    s = fmaxf(s, 0.f);
    hred[tid] = s * fc2w[tid];
  }
  __syncthreads();
  if (tid == 0) {
    float s = fc2b[0];
    for (int i = 0; i < 128; i++) s += hred[i];
    out[0] = s;
  }
}

extern "C" void kernel_launch(void* const* d_in, const int* in_sizes, int n_in,
                              void* d_out, int out_size, void* d_ws, size_t ws_size,
                              hipStream_t stream) {
  const float* x[2] = {(const float*)d_in[0], (const float*)d_in[3]};
  const int* ei[2] = {(const int*)d_in[1], (const int*)d_in[4]};
  const int* et[2] = {(const int*)d_in[2], (const int*)d_in[5]};
  const float* Wp[3] = {(const float*)d_in[6], (const float*)d_in[9], (const float*)d_in[12]};
  const float* rootp[3] = {(const float*)d_in[7], (const float*)d_in[10], (const float*)d_in[13]};
  const float* biasp[3] = {(const float*)d_in[8], (const float*)d_in[11], (const float*)d_in[14]};
  const float* fc1w = (const float*)d_in[15];
  const float* fc1b = (const float*)d_in[16];
  const float* fc2w = (const float*)d_in[17];
  const float* fc2b = (const float*)d_in[18];

  const int N = in_sizes[0] / DH;
  const int E = in_sizes[2];
  const int M = N * R_ET;
  const int MB = (M + 1023) / 1024;  // <= 1024

  char* ws = (char*)d_ws;
  size_t ob = 0;
  auto alloc = [&](size_t bytes) {
    void* p = ws + ob;
    ob = (ob + bytes + 255) & ~(size_t)255;
    return p;
  };
  int* cnt = (int*)alloc((size_t)M * 4);
  int* offs = (int*)alloc((size_t)(M + 1) * 4);
  int* cursor = (int*)alloc((size_t)M * 4);
  int* bsum = (int*)alloc(1024 * 4);
  int* meta = (int*)alloc((size_t)E * 4);
  float* upart = (float*)alloc((size_t)2 * 64 * DH * 4);  // [graph][64][128]
  ushort* A0 = (ushort*)alloc((size_t)N * DH * 2);
  ushort* A1 = (ushort*)alloc((size_t)N * DH * 2);
  ushort* Wt = (ushort*)alloc((size_t)3 * 9 * DH * DH * 2);
  (void)ws_size;

  hipMemsetAsync(upart, 0, (size_t)2 * 64 * DH * sizeof(float), stream);
  for (int l = 0; l < 3; l++)
    wconv_kernel<<<9, 256, 0, stream>>>(rootp[l], Wp[l], Wt + (size_t)l * 9 * DH * DH);

  dim3 egrid((E + 255) / 256);
  const int total = N * DH;
  const int nblk = (N + 15) / 16;

  for (int g = 0; g < 2; g++) {
    hipMemsetAsync(cnt, 0, (size_t)M * sizeof(int), stream);
    count_kernel<<<egrid, 256, 0, stream>>>(ei[g], et[g], cnt, E);
    scan1_kernel<<<MB, 1024, 0, stream>>>(cnt, offs, bsum, M);
    scan2_kernel<<<1, 1024, 0, stream>>>(bsum, MB);
    scan3_kernel<<<MB, 1024, 0, stream>>>(offs, cursor, bsum, M, E);
    place_kernel<<<egrid, 256, 0, stream>>>(ei[g], et[g], cursor, meta, E);
    aconv_kernel<<<(total / 4 + 255) / 256, 256, 0, stream>>>(x[g], A0, total);
    rgcn_fused<0><<<nblk, 256, 0, stream>>>(A0, Wt + 0 * 9 * DH * DH, offs, meta,
                                            biasp[0], A1, nullptr, N, M);
    rgcn_fused<0><<<nblk, 256, 0, stream>>>(A1, Wt + 1 * 9 * DH * DH, offs, meta,
                                            biasp[1], A0, nullptr, N, M);
    rgcn_fused<1><<<nblk, 256, 0, stream>>>(A0, Wt + 2 * 9 * DH * DH, offs, meta,
                                            nullptr, nullptr, upart + (size_t)g * 64 * DH,
                                            N, M);
  }
  mlp_kernel<<<1, 256, 0, stream>>>(upart, biasp[2], fc1w, fc1b, fc2w, fc2b,
                                    (float*)d_out, N);
}